// Round 3
// baseline (209.996 us; speedup 1.0000x reference)
//
#include <hip/hip_runtime.h>
#include <hip/hip_bf16.h>
#include <cstdint>

#define NBATCH 512
#define NDIM   2048
#define NHEADS 16
#define NCPH   128

typedef __bf16 bf16x8 __attribute__((ext_vector_type(8)));
typedef float  f32x4  __attribute__((ext_vector_type(4)));

__device__ __forceinline__ unsigned short f2bf(float f) {
    uint32_t u = __builtin_bit_cast(uint32_t, f);
    u += 0x7FFFu + ((u >> 16) & 1u);   // round-to-nearest-even
    return (unsigned short)(u >> 16);
}

__device__ __forceinline__ void gl_lds16(const void* g, void* l) {
    __builtin_amdgcn_global_load_lds(
        (const __attribute__((address_space(1))) void*)g,
        (__attribute__((address_space(3))) void*)l,
        16, 0, 0);
}

// ---------------- convert f32 -> bf16 for W_qv, W_out, x ----------------
__global__ __launch_bounds__(256) void cvt_all(
    const float* __restrict__ wqv, const float* __restrict__ wout,
    const float* __restrict__ x,
    unsigned short* __restrict__ owqv, unsigned short* __restrict__ owout,
    unsigned short* __restrict__ ox)
{
    int t = blockIdx.x * 256 + threadIdx.x;   // one float4 per thread
    const int n1 = (2*NDIM*NDIM)/4;   // W_qv  : 2097152 float4
    const int n2 = (NDIM*NDIM)/4;     // W_out : 1048576
    const float4* src; unsigned short* dst; int idx;
    if (t < n1)            { src = (const float4*)wqv;  dst = owqv;  idx = t; }
    else if (t < n1 + n2)  { src = (const float4*)wout; dst = owout; idx = t - n1; }
    else                   { src = (const float4*)x;    dst = ox;    idx = t - n1 - n2; }
    float4 v = src[idx];
    ushort4 o;
    o.x = f2bf(v.x); o.y = f2bf(v.y); o.z = f2bf(v.z); o.w = f2bf(v.w);
    *(ushort4*)(dst + (size_t)idx * 4) = o;
}

// ---------------- bf16 GEMM with split-K ------------------------------
// C_partial[sk][m][n] = sum_{k in slice sk} A[m,k]*B[n,k]
// A: M x K bf16 row-major, B: N x K bf16 row-major.
// 128x128 block tile, BK=32, 256 threads = 4 waves (2x2), wave = 64x64 out
// (MI=NI=4 -> 8 ds_read_b128 : 16 MFMA per K-step, near LDS/MFMA balance).
// XOR-swizzle (4 chunks, row&3): pre-swizzled global src, linear LDS dest,
// swizzled ds_read (rule #21). 2-phase pipeline, one barrier per K-step.
template<int BM, int BN, int BK>
__global__ __launch_bounds__(256, 2) void gemm_bt(
    const unsigned short* __restrict__ A, const unsigned short* __restrict__ B,
    float* __restrict__ C, int M, int N, int K, int KS)
{
    constexpr int WM = BM / 2, WN = BN / 2;        // 64, 64
    constexpr int MI = WM / 16, NI = WN / 16;      // 4, 4
    constexpr int NTA = (BM * BK) / 2048;          // 2 staging rounds for A
    constexpr int NTB = (BN * BK) / 2048;

    __shared__ unsigned short As[2][BM * BK];
    __shared__ unsigned short Bs[2][BN * BK];

    const int tid  = threadIdx.x;
    const int lane = tid & 63;
    const int wid  = tid >> 6;
    const int wr   = wid >> 1;
    const int wc   = wid & 1;
    const int m0   = blockIdx.y * BM;
    const int n0   = blockIdx.x * BN;
    const int kbase = blockIdx.z * KS;
    const int fr   = lane & 15;
    const int kq   = lane >> 4;

    f32x4 acc[MI][NI] = {};

    auto stage = [&](int bs, int k0) {
#pragma unroll
        for (int r = 0; r < NTA; r++) {
            const int e   = r * 2048 + tid * 8;
            const int row = e >> 5;                       // /BK
            const int swz = (((e & 31) >> 3) ^ (row & 3)) << 3;
            gl_lds16(A + (size_t)(m0 + row) * K + k0 + swz, &As[bs][e]);
        }
#pragma unroll
        for (int r = 0; r < NTB; r++) {
            const int e   = r * 2048 + tid * 8;
            const int row = e >> 5;
            const int swz = (((e & 31) >> 3) ^ (row & 3)) << 3;
            gl_lds16(B + (size_t)(n0 + row) * K + k0 + swz, &Bs[bs][e]);
        }
    };

    auto compute = [&](int bs) {
        bf16x8 af[MI], bfv[NI];
#pragma unroll
        for (int i = 0; i < MI; i++) {
            const int row = wr * WM + i * 16 + fr;
            af[i] = *(const bf16x8*)&As[bs][row * BK + ((kq ^ (row & 3)) << 3)];
        }
#pragma unroll
        for (int j = 0; j < NI; j++) {
            const int row = wc * WN + j * 16 + fr;
            bfv[j] = *(const bf16x8*)&Bs[bs][row * BK + ((kq ^ (row & 3)) << 3)];
        }
#pragma unroll
        for (int i = 0; i < MI; i++)
#pragma unroll
            for (int j = 0; j < NI; j++)
                acc[i][j] = __builtin_amdgcn_mfma_f32_16x16x32_bf16(
                    af[i], bfv[j], acc[i][j], 0, 0, 0);
    };

    stage(0, kbase);
    __syncthreads();

    const int NT = KS / BK;
    int cur = 0;
    for (int t = 0; t < NT - 1; t++) {
        stage(cur ^ 1, kbase + (t + 1) * BK);  // prefetch overlaps compute
        compute(cur);
        __syncthreads();
        cur ^= 1;
    }
    compute(cur);

    float* Cp = C + (size_t)blockIdx.z * M * N;
    const int row0 = m0 + wr * WM + (kq << 2);
    const int col0 = n0 + wc * WN + fr;
#pragma unroll
    for (int j = 0; j < NI; j++) {
        const int cc = col0 + j * 16;
#pragma unroll
        for (int i = 0; i < MI; i++)
#pragma unroll
            for (int r = 0; r < 4; r++)
                Cp[(size_t)(row0 + i * 16 + r) * N + cc] = acc[i][j][r];
    }
}

// ---------------- split-K reduce (+optional bias, +optional BN sums) ---
// one block per output row b; thread t owns cols [t*NF4*4, (t+1)*NF4*4)
template<int SK, int NF4, bool BN>
__global__ __launch_bounds__(256) void reduce_k(
    const float* __restrict__ part, float* __restrict__ outp,
    const float* __restrict__ bias, float* __restrict__ bnpart, int N)
{
    const int b = blockIdx.x, t = threadIdx.x;
    const size_t row = (size_t)b * N;
    const size_t skstride = (size_t)gridDim.x * N;
    float4 acc[NF4];
#pragma unroll
    for (int f = 0; f < NF4; f++)
        acc[f] = *(const float4*)&part[row + (t * NF4 + f) * 4];
#pragma unroll
    for (int s = 1; s < SK; s++)
#pragma unroll
        for (int f = 0; f < NF4; f++) {
            float4 p = *(const float4*)&part[s * skstride + row + (t * NF4 + f) * 4];
            acc[f].x += p.x; acc[f].y += p.y; acc[f].z += p.z; acc[f].w += p.w;
        }
    if (bias) {
#pragma unroll
        for (int f = 0; f < NF4; f++) {
            float4 bb = *(const float4*)&bias[(t * NF4 + f) * 4];
            acc[f].x += bb.x; acc[f].y += bb.y; acc[f].z += bb.z; acc[f].w += bb.w;
        }
    }
#pragma unroll
    for (int f = 0; f < NF4; f++)
        *(float4*)&outp[row + (t * NF4 + f) * 4] = acc[f];

    if (BN) {
        // v-half = cols [2048,4096) -> threads 128..255; 8 threads per head
        if (t >= 128) {
            float s = 0.f, ss = 0.f;
#pragma unroll
            for (int f = 0; f < NF4; f++) {
                s  += acc[f].x + acc[f].y + acc[f].z + acc[f].w;
                ss = fmaf(acc[f].x, acc[f].x, fmaf(acc[f].y, acc[f].y,
                     fmaf(acc[f].z, acc[f].z, fmaf(acc[f].w, acc[f].w, ss))));
            }
#pragma unroll
            for (int off = 1; off < 8; off <<= 1) {
                s  += __shfl_xor(s, off);
                ss += __shfl_xor(ss, off);
            }
            if ((t & 7) == 0)
                ((float2*)bnpart)[b * NHEADS + ((t - 128) >> 3)] = make_float2(s, ss);
        }
    }
}

// ---------------- finalize BN: per-head scale/shift --------------------
__global__ __launch_bounds__(256) void bn_final(
    const float* __restrict__ bnpart, const float* __restrict__ gamma,
    const float* __restrict__ beta, float* __restrict__ sc2)
{
    const int h = blockIdx.x, t = threadIdx.x;
    float2 p0 = ((const float2*)bnpart)[t * NHEADS + h];
    float2 p1 = ((const float2*)bnpart)[(t + 256) * NHEADS + h];
    float s = p0.x + p1.x, ss = p0.y + p1.y;
#pragma unroll
    for (int off = 32; off; off >>= 1) {
        s  += __shfl_down(s, off);
        ss += __shfl_down(ss, off);
    }
    __shared__ float ls[4], lss[4];
    if ((t & 63) == 0) { ls[t >> 6] = s; lss[t >> 6] = ss; }
    __syncthreads();
    if (t == 0) {
        float S  = ls[0] + ls[1] + ls[2] + ls[3];
        float SS = lss[0] + lss[1] + lss[2] + lss[3];
        const float inv = 1.0f / (NBATCH * NCPH);
        float mean = S * inv;
        float var  = SS * inv - mean * mean;
        float sc   = gamma[h] * rsqrtf(var + 1e-5f);
        ((float2*)sc2)[h] = make_float2(sc, beta[h] - mean * sc);
    }
}

// ---------------- fused outer-product + bias + softmax + PV ------------
// one block per (b,h); 256 threads; thread pair (2c, 2c+1) owns row c.
// BN fold: out = sc * (sum p*v_raw / sum p) + sh
__global__ __launch_bounds__(256) void attn_k(
    const float* __restrict__ qv, const float* __restrict__ kparam,
    const float* __restrict__ bias, const float* __restrict__ temperature,
    const float* __restrict__ sc2, unsigned short* __restrict__ aout)
{
    const int bh = blockIdx.x;
    const int b  = bh >> 4;
    const int h  = bh & 15;
    const int tid = threadIdx.x;

    __shared__ float ks[NCPH], vsr[NCPH];
    if (tid < NCPH) {
        ks[tid]  = kparam[(size_t)b * NDIM + h * NCPH + tid];
        vsr[tid] = qv[(size_t)b * (2 * NDIM) + NDIM + h * NCPH + tid];
    }
    const int c = tid >> 1, half = tid & 1;
    const float qc   = qv[(size_t)b * (2 * NDIM) + h * NCPH + c];
    const float temp = temperature[h];
    __syncthreads();

    const float4* bp = (const float4*)(bias + ((size_t)bh << 14)
                                       + (size_t)c * NCPH + half * 64);
    float4 l4[16];
#pragma unroll
    for (int j = 0; j < 16; j++) l4[j] = bp[j];
    float* l = (float*)l4;

    const float* kk = ks  + half * 64;
    const float* vv = vsr + half * 64;

    float m = -1e30f;
#pragma unroll
    for (int j = 0; j < 64; j++) {
        l[j] = fmaf(qc, kk[j], l[j]) * temp;
        m = fmaxf(m, l[j]);
    }
    m = fmaxf(m, __shfl_xor(m, 1));

    float s = 0.f, o = 0.f;
#pragma unroll
    for (int j = 0; j < 64; j++) {
        float p = __expf(l[j] - m);
        s += p;
        o = fmaf(p, vv[j], o);
    }
    s += __shfl_xor(s, 1);
    o += __shfl_xor(o, 1);

    if (half == 0) {
        const float2 s2 = ((const float2*)sc2)[h];
        aout[(size_t)b * NDIM + h * NCPH + c] = f2bf(fmaf(s2.x, o / s, s2.y));
    }
}

// ------------------------------ launch ---------------------------------
extern "C" void kernel_launch(void* const* d_in, const int* in_sizes, int n_in,
                              void* d_out, int out_size, void* d_ws, size_t ws_size,
                              hipStream_t stream)
{
    const float* x      = (const float*)d_in[0];
    const float* Wqv    = (const float*)d_in[1];
    const float* temp   = (const float*)d_in[2];
    const float* kparam = (const float*)d_in[3];
    const float* bias   = (const float*)d_in[4];
    const float* gamma  = (const float*)d_in[5];
    const float* beta   = (const float*)d_in[6];
    const float* Wout   = (const float*)d_in[7];
    const float* bout   = (const float*)d_in[8];
    float* out = (float*)d_out;

    char* ws = (char*)d_ws;
    unsigned short* wqv_bf  = (unsigned short*)(ws);              // 16 MiB
    unsigned short* wout_bf = (unsigned short*)(ws + 16777216);   //  8 MiB
    unsigned short* x_bf    = (unsigned short*)(ws + 25165824);   //  2 MiB
    float*          qv      = (float*)(ws + 27262976);            //  8 MiB
    unsigned short* ao_bf   = (unsigned short*)(ws + 35651584);   //  2 MiB
    float*          part    = (float*)(ws + 37748736);            // 32 MiB
    float*          bnpart  = (float*)(ws + 71303168);            // 64 KiB
    float*          sc2     = (float*)(ws + 71368704);            // 128 B

    cvt_all<<<13312, 256, 0, stream>>>(Wqv, Wout, x, wqv_bf, wout_bf, x_bf);

    // qv = x @ W_qv^T : M=512, N=4096, K=2048, split-K=4 (512 blocks)
    gemm_bt<128, 128, 32><<<dim3(32, 4, 4), 256, 0, stream>>>(
        x_bf, wqv_bf, part, NBATCH, 2 * NDIM, NDIM, NDIM / 4);

    // reduce partials -> qv, fused per-(b,h) BN sums
    reduce_k<4, 4, true><<<NBATCH, 256, 0, stream>>>(
        part, qv, nullptr, bnpart, 2 * NDIM);

    bn_final<<<NHEADS, 256, 0, stream>>>(bnpart, gamma, beta, sc2);

    attn_k<<<NBATCH * NHEADS, 256, 0, stream>>>(
        qv, kparam, bias, temp, sc2, ao_bf);

    // out = attn_out @ W_out^T + b_out : M=512, N=2048, K=2048, split-K=8
    gemm_bt<128, 128, 32><<<dim3(16, 4, 8), 256, 0, stream>>>(
        ao_bf, wout_bf, part, NBATCH, NDIM, NDIM, NDIM / 8);

    reduce_k<8, 2, false><<<NBATCH, 256, 0, stream>>>(
        part, out, bout, nullptr, NDIM);
}